// Round 1
// baseline (948.339 us; speedup 1.0000x reference)
//
#include <hip/hip_runtime.h>

#define IN_C 128
#define HID  64
#define NCLS 40

// ---------------- degree / normalization ----------------

__global__ void deg_kernel(const int* __restrict__ dst, int* __restrict__ deg, int E) {
    int e = blockIdx.x * blockDim.x + threadIdx.x;
    if (e < E) atomicAdd(&deg[dst[e]], 1);
}

__global__ void dis_kernel(const int* __restrict__ deg, float* __restrict__ dis, int n) {
    int i = blockIdx.x * blockDim.x + threadIdx.x;
    if (i < n) dis[i] = rsqrtf((float)(deg[i] + 1));   // +1 self-loop; deg>=1 always
}

// ---------------- GEMM1: hs1 = (x @ W1) * dis[i] ----------------
// block = 256 (4 waves), wave w handles row blockIdx*4+w, lane j computes col j.

__global__ __launch_bounds__(256) void gemm1_kernel(
    const float* __restrict__ x, const float* __restrict__ W1,
    const float* __restrict__ dis, float* __restrict__ hs1, int n)
{
    __shared__ float sW[IN_C * HID];     // 32 KB
    __shared__ float sRow[4][IN_C];      // 2 KB
    for (int idx = threadIdx.x; idx < IN_C * HID; idx += 256) sW[idx] = W1[idx];
    int wave = threadIdx.x >> 6, lane = threadIdx.x & 63;
    int row = blockIdx.x * 4 + wave;
    if (row < n) {
        for (int k = lane; k < IN_C; k += 64) sRow[wave][k] = x[row * IN_C + k];
    }
    __syncthreads();
    if (row >= n) return;
    float acc = 0.f;
#pragma unroll
    for (int k = 0; k < IN_C; ++k) acc += sRow[wave][k] * sW[k * HID + lane];
    hs1[row * HID + lane] = acc * dis[row];
}

// ---------------- scatter layer1: agg[dst] += hs1[src], 64 feats ----------------

__global__ __launch_bounds__(256) void scatter1_kernel(
    const int* __restrict__ src, const int* __restrict__ dst,
    const float* __restrict__ hs1, float* __restrict__ agg, int E)
{
    int tid = blockIdx.x * blockDim.x + threadIdx.x;
    int e = tid >> 6, f = tid & 63;
    if (e >= E) return;
    int s = src[e], d = dst[e];
    atomicAdd(&agg[d * HID + f], hs1[s * HID + f]);
}

// ---------------- finalize1: h1 = relu((agg+hs1)*dis + b1), in-place into agg ----

__global__ __launch_bounds__(256) void finalize1_kernel(
    float* __restrict__ agg, const float* __restrict__ hs1,
    const float* __restrict__ dis, const float* __restrict__ b1, int n)
{
    int tid = blockIdx.x * blockDim.x + threadIdx.x;
    if (tid >= n * HID) return;
    int i = tid >> 6, f = tid & 63;
    float v = (agg[tid] + hs1[tid]) * dis[i] + b1[f];
    agg[tid] = v > 0.f ? v : 0.f;
}

// ---------------- GEMM2: hs2 = (h1 @ W2) * dis[i] ----------------

__global__ __launch_bounds__(256) void gemm2_kernel(
    const float* __restrict__ h1, const float* __restrict__ W2,
    const float* __restrict__ dis, float* __restrict__ hs2, int n)
{
    __shared__ float sW[HID * NCLS];     // 10.24 KB
    __shared__ float sRow[4][HID];
    for (int idx = threadIdx.x; idx < HID * NCLS; idx += 256) sW[idx] = W2[idx];
    int wave = threadIdx.x >> 6, lane = threadIdx.x & 63;
    int row = blockIdx.x * 4 + wave;
    if (row < n && lane < HID) sRow[wave][lane] = h1[row * HID + lane];
    __syncthreads();
    if (row >= n || lane >= NCLS) return;
    float acc = 0.f;
#pragma unroll
    for (int k = 0; k < HID; ++k) acc += sRow[wave][k] * sW[k * NCLS + lane];
    hs2[row * NCLS + lane] = acc * dis[row];
}

// ---------------- scatter layer2: out[dst] += hs2[src], 40 feats ----------------

__global__ __launch_bounds__(256) void scatter2_kernel(
    const int* __restrict__ src, const int* __restrict__ dst,
    const float* __restrict__ hs2, float* __restrict__ out, int E)
{
    int tid = blockIdx.x * blockDim.x + threadIdx.x;
    int e = tid >> 6, f = tid & 63;
    if (e >= E || f >= NCLS) return;
    int s = src[e], d = dst[e];
    atomicAdd(&out[d * NCLS + f], hs2[s * NCLS + f]);
}

// ---------------- finalize2: out = (out + hs2)*dis + b2, in place ----------------

__global__ __launch_bounds__(256) void finalize2_kernel(
    float* __restrict__ out, const float* __restrict__ hs2,
    const float* __restrict__ dis, const float* __restrict__ b2, int n)
{
    int tid = blockIdx.x * blockDim.x + threadIdx.x;
    if (tid >= n * NCLS) return;
    int i = tid / NCLS, f = tid - i * NCLS;
    out[tid] = (out[tid] + hs2[tid]) * dis[i] + b2[f];
}

extern "C" void kernel_launch(void* const* d_in, const int* in_sizes, int n_in,
                              void* d_out, int out_size, void* d_ws, size_t ws_size,
                              hipStream_t stream) {
    const float* x  = (const float*)d_in[0];
    const int*   ei = (const int*)d_in[1];
    const float* W1 = (const float*)d_in[2];
    const float* b1 = (const float*)d_in[3];
    const float* W2 = (const float*)d_in[4];
    const float* b2 = (const float*)d_in[5];
    float* out = (float*)d_out;

    const int n = in_sizes[0] / IN_C;        // 100000
    const int E = in_sizes[1] / 2;           // 1600000
    const int* src = ei;
    const int* dst = ei + E;

    // workspace layout
    char* ws = (char*)d_ws;
    float* dis  = (float*)ws;                          // n floats
    float* bufA = (float*)(ws + (size_t)n * 4);        // n*HID floats: hs1, later hs2
    float* bufB = (float*)(ws + (size_t)n * 4 + (size_t)n * HID * 4); // deg/agg1/h1
    int*   deg  = (int*)bufB;

    // 1. deg = 0 ; count in-degree
    hipMemsetAsync(deg, 0, (size_t)n * 4, stream);
    deg_kernel<<<(E + 255) / 256, 256, 0, stream>>>(dst, deg, E);
    // 2. dis = rsqrt(deg+1)
    dis_kernel<<<(n + 255) / 256, 256, 0, stream>>>(deg, dis, n);
    // 3. hs1 = (x@W1)*dis
    gemm1_kernel<<<(n + 3) / 4, 256, 0, stream>>>(x, W1, dis, bufA, n);
    // 4. agg1 = 0 ; scatter
    hipMemsetAsync(bufB, 0, (size_t)n * HID * 4, stream);
    {
        long long total = (long long)E * 64;
        scatter1_kernel<<<(int)((total + 255) / 256), 256, 0, stream>>>(src, dst, bufA, bufB, E);
    }
    // 5. h1 = relu((agg1+hs1)*dis+b1)   (in-place in bufB)
    finalize1_kernel<<<(n * HID + 255) / 256, 256, 0, stream>>>(bufB, bufA, dis, b1, n);
    // 6. hs2 = (h1@W2)*dis  -> bufA
    gemm2_kernel<<<(n + 3) / 4, 256, 0, stream>>>(bufB, W2, dis, bufA, n);
    // 7. out = 0 ; scatter
    hipMemsetAsync(out, 0, (size_t)n * NCLS * 4, stream);
    {
        long long total = (long long)E * 64;
        scatter2_kernel<<<(int)((total + 255) / 256), 256, 0, stream>>>(src, dst, bufA, out, E);
    }
    // 8. out = (out + hs2)*dis + b2
    finalize2_kernel<<<(n * NCLS + 255) / 256, 256, 0, stream>>>(out, bufA, dis, b2, n);
}

// Round 2
// 635.412 us; speedup vs baseline: 1.4925x; 1.4925x over previous
//
#include <hip/hip_runtime.h>

#define IN_C 128
#define HID  64
#define NCLS 40

// ================= degree / normalization =================

__global__ void deg_kernel(const int* __restrict__ dst, int* __restrict__ deg, int E) {
    int e = blockIdx.x * blockDim.x + threadIdx.x;
    if (e < E) atomicAdd(&deg[dst[e]], 1);
}

__global__ void dis_kernel(const int* __restrict__ deg, float* __restrict__ dis, int n) {
    int i = blockIdx.x * blockDim.x + threadIdx.x;
    if (i < n) dis[i] = rsqrtf((float)(deg[i] + 1));   // +1 self-loop
}

// ================= exclusive scan of deg -> ptr (3-pass) =================
// chunk = 1024 elements per block (256 threads x 4)

__global__ __launch_bounds__(256) void scan_pass1(
    const int* __restrict__ deg, int* __restrict__ bsum, int n)
{
    __shared__ int sdata[256];
    int base = blockIdx.x * 1024, t = threadIdx.x;
    int s = 0;
#pragma unroll
    for (int j = 0; j < 4; ++j) {
        int idx = base + t * 4 + j;
        if (idx < n) s += deg[idx];
    }
    sdata[t] = s; __syncthreads();
    for (int off = 128; off > 0; off >>= 1) {
        if (t < off) sdata[t] += sdata[t + off];
        __syncthreads();
    }
    if (t == 0) bsum[blockIdx.x] = sdata[0];
}

__global__ __launch_bounds__(128) void scan_pass2(int* __restrict__ bsum, int nb)
{
    __shared__ int sdata[128];
    int t = threadIdx.x;
    int v = (t < nb) ? bsum[t] : 0;
    sdata[t] = v; __syncthreads();
    for (int off = 1; off < 128; off <<= 1) {
        int add = (t >= off) ? sdata[t - off] : 0;
        __syncthreads();
        sdata[t] += add;
        __syncthreads();
    }
    if (t < nb) bsum[t] = sdata[t] - v;   // exclusive
}

__global__ __launch_bounds__(256) void scan_pass3(
    const int* __restrict__ deg, const int* __restrict__ bsum,
    int* __restrict__ ptr, int* __restrict__ fill, int n, int E)
{
    __shared__ int sdata[256];
    int base = blockIdx.x * 1024, t = threadIdx.x;
    int v[4]; int ts = 0;
#pragma unroll
    for (int j = 0; j < 4; ++j) {
        int idx = base + t * 4 + j;
        v[j] = (idx < n) ? deg[idx] : 0;
        ts += v[j];
    }
    sdata[t] = ts; __syncthreads();
    for (int off = 1; off < 256; off <<= 1) {
        int add = (t >= off) ? sdata[t - off] : 0;
        __syncthreads();
        sdata[t] += add;
        __syncthreads();
    }
    int running = bsum[blockIdx.x] + sdata[t] - ts;   // exclusive offset
#pragma unroll
    for (int j = 0; j < 4; ++j) {
        int idx = base + t * 4 + j;
        if (idx < n) { ptr[idx] = running; fill[idx] = running; running += v[j]; }
    }
    if (blockIdx.x == 0 && t == 0) ptr[n] = E;
}

// ================= bucket fill: col[] = src sorted by dst =================

__global__ void fill_kernel(const int* __restrict__ src, const int* __restrict__ dst,
                            int* __restrict__ fill, int* __restrict__ col, int E)
{
    int e = blockIdx.x * blockDim.x + threadIdx.x;
    if (e < E) {
        int p = atomicAdd(&fill[dst[e]], 1);
        col[p] = src[e];
    }
}

// ================= GEMM1: hs1 = (x @ W1) * dis[i] =================

__global__ __launch_bounds__(256) void gemm1_kernel(
    const float* __restrict__ x, const float* __restrict__ W1,
    const float* __restrict__ dis, float* __restrict__ hs1, int n)
{
    __shared__ float sW[IN_C * HID];     // 32 KB
    __shared__ float sRow[4][IN_C];
    for (int idx = threadIdx.x; idx < IN_C * HID; idx += 256) sW[idx] = W1[idx];
    int wave = threadIdx.x >> 6, lane = threadIdx.x & 63;
    int row = blockIdx.x * 4 + wave;
    if (row < n) {
        for (int k = lane; k < IN_C; k += 64) sRow[wave][k] = x[row * IN_C + k];
    }
    __syncthreads();
    if (row >= n) return;
    float acc = 0.f;
#pragma unroll
    for (int k = 0; k < IN_C; ++k) acc += sRow[wave][k] * sW[k * HID + lane];
    hs1[row * HID + lane] = acc * dis[row];
}

// ================= agg1 (fused self-loop + dis + bias + relu) =================
// wave per node, lane = feature (64)

__global__ __launch_bounds__(256) void agg1_kernel(
    const int* __restrict__ ptr, const int* __restrict__ col,
    const float* __restrict__ hs1, const float* __restrict__ dis,
    const float* __restrict__ b1, float* __restrict__ h1, int n)
{
    int wave = threadIdx.x >> 6, lane = threadIdx.x & 63;
    int i = blockIdx.x * 4 + wave;
    if (i >= n) return;
    int start = ptr[i], end = ptr[i + 1];
    float acc = hs1[(size_t)i * HID + lane];      // self-loop term
    for (int base = start; base < end; base += 64) {
        int m = end - base; if (m > 64) m = 64;
        int myc = (lane < m) ? col[base + lane] : 0;
        for (int j = 0; j < m; ++j) {
            int s = __shfl(myc, j);
            acc += hs1[(size_t)s * HID + lane];
        }
    }
    float val = acc * dis[i] + b1[lane];
    h1[(size_t)i * HID + lane] = val > 0.f ? val : 0.f;
}

// ================= GEMM2: hs2 = (h1 @ W2) * dis[i] =================

__global__ __launch_bounds__(256) void gemm2_kernel(
    const float* __restrict__ h1, const float* __restrict__ W2,
    const float* __restrict__ dis, float* __restrict__ hs2, int n)
{
    __shared__ float sW[HID * NCLS];
    __shared__ float sRow[4][HID];
    for (int idx = threadIdx.x; idx < HID * NCLS; idx += 256) sW[idx] = W2[idx];
    int wave = threadIdx.x >> 6, lane = threadIdx.x & 63;
    int row = blockIdx.x * 4 + wave;
    if (row < n && lane < HID) sRow[wave][lane] = h1[(size_t)row * HID + lane];
    __syncthreads();
    if (row >= n || lane >= NCLS) return;
    float acc = 0.f;
#pragma unroll
    for (int k = 0; k < HID; ++k) acc += sRow[wave][k] * sW[k * NCLS + lane];
    hs2[(size_t)row * NCLS + lane] = acc * dis[row];
}

// ================= agg2 (fused self-loop + dis + bias) -> out =================

__global__ __launch_bounds__(256) void agg2_kernel(
    const int* __restrict__ ptr, const int* __restrict__ col,
    const float* __restrict__ hs2, const float* __restrict__ dis,
    const float* __restrict__ b2, float* __restrict__ out, int n)
{
    int wave = threadIdx.x >> 6, lane = threadIdx.x & 63;
    int i = blockIdx.x * 4 + wave;
    if (i >= n) return;
    int start = ptr[i], end = ptr[i + 1];
    float acc = 0.f;
    if (lane < NCLS) acc = hs2[(size_t)i * NCLS + lane];   // self-loop
    for (int base = start; base < end; base += 64) {
        int m = end - base; if (m > 64) m = 64;
        int myc = (lane < m) ? col[base + lane] : 0;
        for (int j = 0; j < m; ++j) {
            int s = __shfl(myc, j);
            if (lane < NCLS) acc += hs2[(size_t)s * NCLS + lane];
        }
    }
    if (lane < NCLS) out[(size_t)i * NCLS + lane] = acc * dis[i] + b2[lane];
}

// ================= launch =================

extern "C" void kernel_launch(void* const* d_in, const int* in_sizes, int n_in,
                              void* d_out, int out_size, void* d_ws, size_t ws_size,
                              hipStream_t stream) {
    const float* x  = (const float*)d_in[0];
    const int*   ei = (const int*)d_in[1];
    const float* W1 = (const float*)d_in[2];
    const float* b1 = (const float*)d_in[3];
    const float* W2 = (const float*)d_in[4];
    const float* b2 = (const float*)d_in[5];
    float* out = (float*)d_out;

    const int n = in_sizes[0] / IN_C;        // 100000
    const int E = in_sizes[1] / 2;           // 1600000
    const int* src = ei;
    const int* dst = ei + E;

    // workspace layout (bytes, 256-aligned)
    char* ws = (char*)d_ws;
    size_t off = 0;
    auto alloc = [&](size_t bytes) { char* p = ws + off; off += (bytes + 255) & ~(size_t)255; return p; };
    float* dis  = (float*)alloc((size_t)n * 4);
    int*   ptr  = (int*)  alloc((size_t)(n + 1) * 4);
    int*   col  = (int*)  alloc((size_t)E * 4);
    float* bufA = (float*)alloc((size_t)n * HID * 4);   // hs1, later hs2
    float* bufB = (float*)alloc((size_t)n * HID * 4);   // scratch(deg/fill/bsum) then h1
    // transient ints live inside bufB (dead before agg1 writes h1):
    int* deg  = (int*)bufB;
    int* fill = (int*)bufB + n;
    int* bsum = (int*)bufB + 2 * n;

    const int nb = (n + 1023) / 1024;        // scan blocks (98)

    hipMemsetAsync(deg, 0, (size_t)n * 4, stream);
    deg_kernel<<<(E + 255) / 256, 256, 0, stream>>>(dst, deg, E);
    dis_kernel<<<(n + 255) / 256, 256, 0, stream>>>(deg, dis, n);
    scan_pass1<<<nb, 256, 0, stream>>>(deg, bsum, n);
    scan_pass2<<<1, 128, 0, stream>>>(bsum, nb);
    scan_pass3<<<nb, 256, 0, stream>>>(deg, bsum, ptr, fill, n, E);
    fill_kernel<<<(E + 255) / 256, 256, 0, stream>>>(src, dst, fill, col, E);

    gemm1_kernel<<<(n + 3) / 4, 256, 0, stream>>>(x, W1, dis, bufA, n);
    agg1_kernel<<<(n + 3) / 4, 256, 0, stream>>>(ptr, col, bufA, dis, b1, bufB, n);
    gemm2_kernel<<<(n + 3) / 4, 256, 0, stream>>>(bufB, W2, dis, bufA, n);
    agg2_kernel<<<(n + 3) / 4, 256, 0, stream>>>(ptr, col, bufA, dis, b2, out, n);
}

// Round 3
// 540.418 us; speedup vs baseline: 1.7548x; 1.1758x over previous
//
#include <hip/hip_runtime.h>

#define IN_C 128
#define HID  64
#define NCLS 40

typedef float f32x4 __attribute__((ext_vector_type(4)));
typedef short s16x8 __attribute__((ext_vector_type(8)));

// truncation split: v = hi + lo with hi = top-16-bit truncation (exactly representable)
static __device__ inline void split1(float v, unsigned short& hb, unsigned short& lb) {
    hb = (unsigned short)(__float_as_uint(v) >> 16);
    float vhi = __uint_as_float((unsigned)hb << 16);
    lb = (unsigned short)(__float_as_uint(v - vhi) >> 16);
}

static __device__ inline void split8(const f32x4 a0, const f32x4 a1, s16x8& hi, s16x8& lo) {
    float v[8] = {a0.x, a0.y, a0.z, a0.w, a1.x, a1.y, a1.z, a1.w};
#pragma unroll
    for (int j = 0; j < 8; ++j) {
        unsigned short hb, lb;
        split1(v[j], hb, lb);
        hi[j] = (short)hb;
        lo[j] = (short)lb;
    }
}

// ================= degree / normalization =================

__global__ void deg_kernel(const int* __restrict__ dst, int* __restrict__ deg, int E) {
    int e = blockIdx.x * blockDim.x + threadIdx.x;
    if (e < E) atomicAdd(&deg[dst[e]], 1);
}

__global__ void dis_kernel(const int* __restrict__ deg, float* __restrict__ dis, int n) {
    int i = blockIdx.x * blockDim.x + threadIdx.x;
    if (i < n) dis[i] = rsqrtf((float)(deg[i] + 1));   // +1 self-loop
}

// ================= exclusive scan of deg -> ptr (3-pass) =================

__global__ __launch_bounds__(256) void scan_pass1(
    const int* __restrict__ deg, int* __restrict__ bsum, int n)
{
    __shared__ int sdata[256];
    int base = blockIdx.x * 1024, t = threadIdx.x;
    int s = 0;
#pragma unroll
    for (int j = 0; j < 4; ++j) {
        int idx = base + t * 4 + j;
        if (idx < n) s += deg[idx];
    }
    sdata[t] = s; __syncthreads();
    for (int off = 128; off > 0; off >>= 1) {
        if (t < off) sdata[t] += sdata[t + off];
        __syncthreads();
    }
    if (t == 0) bsum[blockIdx.x] = sdata[0];
}

__global__ __launch_bounds__(128) void scan_pass2(int* __restrict__ bsum, int nb)
{
    __shared__ int sdata[128];
    int t = threadIdx.x;
    int v = (t < nb) ? bsum[t] : 0;
    sdata[t] = v; __syncthreads();
    for (int off = 1; off < 128; off <<= 1) {
        int add = (t >= off) ? sdata[t - off] : 0;
        __syncthreads();
        sdata[t] += add;
        __syncthreads();
    }
    if (t < nb) bsum[t] = sdata[t] - v;   // exclusive
}

__global__ __launch_bounds__(256) void scan_pass3(
    const int* __restrict__ deg, const int* __restrict__ bsum,
    int* __restrict__ ptr, int* __restrict__ fill, int n, int E)
{
    __shared__ int sdata[256];
    int base = blockIdx.x * 1024, t = threadIdx.x;
    int v[4]; int ts = 0;
#pragma unroll
    for (int j = 0; j < 4; ++j) {
        int idx = base + t * 4 + j;
        v[j] = (idx < n) ? deg[idx] : 0;
        ts += v[j];
    }
    sdata[t] = ts; __syncthreads();
    for (int off = 1; off < 256; off <<= 1) {
        int add = (t >= off) ? sdata[t - off] : 0;
        __syncthreads();
        sdata[t] += add;
        __syncthreads();
    }
    int running = bsum[blockIdx.x] + sdata[t] - ts;
#pragma unroll
    for (int j = 0; j < 4; ++j) {
        int idx = base + t * 4 + j;
        if (idx < n) { ptr[idx] = running; fill[idx] = running; running += v[j]; }
    }
    if (blockIdx.x == 0 && t == 0) ptr[n] = E;
}

// ================= bucket fill: col[] = src sorted by dst =================

__global__ void fill_kernel(const int* __restrict__ src, const int* __restrict__ dst,
                            int* __restrict__ fill, int* __restrict__ col, int E)
{
    int e = blockIdx.x * blockDim.x + threadIdx.x;
    if (e < E) {
        int p = atomicAdd(&fill[dst[e]], 1);
        col[p] = src[e];
    }
}

// ================= GEMM1 (MFMA): hs1 = (x @ W1) * dis[i] =================
// block = 256 = 4 waves; wave w owns output cols [16w, 16w+16); grid-stride over
// 16-row slabs. Split-bf16: xh@Wh + xl@Wh + xh@Wl (f32 accumulate, err ~2^-17).

__global__ __launch_bounds__(256) void gemm1_mfma(
    const float* __restrict__ x, const float* __restrict__ W1,
    const float* __restrict__ dis, float* __restrict__ hs1, int n)
{
    const int wave = threadIdx.x >> 6;
    const int lane = threadIdx.x & 63;
    const int m    = lane & 15;
    const int q    = lane >> 4;
    const int col  = wave * 16 + m;

    // B fragments: W1 col `col`, 4 K-chunks of 32, hi+lo
    s16x8 bhi[4], blo[4];
#pragma unroll
    for (int t = 0; t < 4; ++t) {
#pragma unroll
        for (int j = 0; j < 8; ++j) {
            int k = t * 32 + q * 8 + j;
            unsigned short hb, lb;
            split1(W1[k * HID + col], hb, lb);
            bhi[t][j] = (short)hb;
            blo[t][j] = (short)lb;
        }
    }

    const int nslab = n >> 4;   // n = 100000 -> 6250 slabs of 16 rows
    for (int s = blockIdx.x; s < nslab; s += gridDim.x) {
        const float* xrow = x + (size_t)(s * 16 + m) * IN_C;
        f32x4 acc = {0.f, 0.f, 0.f, 0.f};
#pragma unroll
        for (int t = 0; t < 4; ++t) {
            f32x4 a0 = *(const f32x4*)(xrow + t * 32 + q * 8);
            f32x4 a1 = *(const f32x4*)(xrow + t * 32 + q * 8 + 4);
            s16x8 ahi, alo;
            split8(a0, a1, ahi, alo);
            acc = __builtin_amdgcn_mfma_f32_16x16x32_bf16(ahi, bhi[t], acc, 0, 0, 0);
            acc = __builtin_amdgcn_mfma_f32_16x16x32_bf16(alo, bhi[t], acc, 0, 0, 0);
            acc = __builtin_amdgcn_mfma_f32_16x16x32_bf16(ahi, blo[t], acc, 0, 0, 0);
        }
#pragma unroll
        for (int r = 0; r < 4; ++r) {
            int row = s * 16 + q * 4 + r;
            hs1[(size_t)row * HID + col] = acc[r] * dis[row];
        }
    }
}

// ================= agg1 (fused self-loop + dis + bias + relu) =================

__global__ __launch_bounds__(256) void agg1_kernel(
    const int* __restrict__ ptr, const int* __restrict__ col,
    const float* __restrict__ hs1, const float* __restrict__ dis,
    const float* __restrict__ b1, float* __restrict__ h1, int n)
{
    int wave = threadIdx.x >> 6, lane = threadIdx.x & 63;
    int i = blockIdx.x * 4 + wave;
    if (i >= n) return;
    int start = ptr[i], end = ptr[i + 1];
    float acc = hs1[(size_t)i * HID + lane];      // self-loop term
    for (int base = start; base < end; base += 64) {
        int m = end - base; if (m > 64) m = 64;
        int myc = (lane < m) ? col[base + lane] : 0;
        for (int j = 0; j < m; ++j) {
            int s = __shfl(myc, j);
            acc += hs1[(size_t)s * HID + lane];
        }
    }
    float val = acc * dis[i] + b1[lane];
    h1[(size_t)i * HID + lane] = val > 0.f ? val : 0.f;
}

// ================= GEMM2 (MFMA): hs2 = (h1 @ W2) * dis[i] =================
// block = 192 = 3 waves; wave w owns cols [16w, 16w+16) (cols >= 40 masked).

__global__ __launch_bounds__(192) void gemm2_mfma(
    const float* __restrict__ h1, const float* __restrict__ W2,
    const float* __restrict__ dis, float* __restrict__ hs2, int n)
{
    const int wave = threadIdx.x >> 6;
    const int lane = threadIdx.x & 63;
    const int m    = lane & 15;
    const int q    = lane >> 4;
    const int col  = wave * 16 + m;

    s16x8 bhi[2], blo[2];
#pragma unroll
    for (int t = 0; t < 2; ++t) {
#pragma unroll
        for (int j = 0; j < 8; ++j) {
            int k = t * 32 + q * 8 + j;
            float w = (col < NCLS) ? W2[k * NCLS + col] : 0.f;
            unsigned short hb, lb;
            split1(w, hb, lb);
            bhi[t][j] = (short)hb;
            blo[t][j] = (short)lb;
        }
    }

    const int nslab = n >> 4;
    for (int s = blockIdx.x; s < nslab; s += gridDim.x) {
        const float* hrow = h1 + (size_t)(s * 16 + m) * HID;
        f32x4 acc = {0.f, 0.f, 0.f, 0.f};
#pragma unroll
        for (int t = 0; t < 2; ++t) {
            f32x4 a0 = *(const f32x4*)(hrow + t * 32 + q * 8);
            f32x4 a1 = *(const f32x4*)(hrow + t * 32 + q * 8 + 4);
            s16x8 ahi, alo;
            split8(a0, a1, ahi, alo);
            acc = __builtin_amdgcn_mfma_f32_16x16x32_bf16(ahi, bhi[t], acc, 0, 0, 0);
            acc = __builtin_amdgcn_mfma_f32_16x16x32_bf16(alo, bhi[t], acc, 0, 0, 0);
            acc = __builtin_amdgcn_mfma_f32_16x16x32_bf16(ahi, blo[t], acc, 0, 0, 0);
        }
        if (col < NCLS) {
#pragma unroll
            for (int r = 0; r < 4; ++r) {
                int row = s * 16 + q * 4 + r;
                hs2[(size_t)row * NCLS + col] = acc[r] * dis[row];
            }
        }
    }
}

// ================= agg2 (fused self-loop + dis + bias) -> out =================

__global__ __launch_bounds__(256) void agg2_kernel(
    const int* __restrict__ ptr, const int* __restrict__ col,
    const float* __restrict__ hs2, const float* __restrict__ dis,
    const float* __restrict__ b2, float* __restrict__ out, int n)
{
    int wave = threadIdx.x >> 6, lane = threadIdx.x & 63;
    int i = blockIdx.x * 4 + wave;
    if (i >= n) return;
    int start = ptr[i], end = ptr[i + 1];
    float acc = 0.f;
    if (lane < NCLS) acc = hs2[(size_t)i * NCLS + lane];   // self-loop
    for (int base = start; base < end; base += 64) {
        int m = end - base; if (m > 64) m = 64;
        int myc = (lane < m) ? col[base + lane] : 0;
        for (int j = 0; j < m; ++j) {
            int s = __shfl(myc, j);
            if (lane < NCLS) acc += hs2[(size_t)s * NCLS + lane];
        }
    }
    if (lane < NCLS) out[(size_t)i * NCLS + lane] = acc * dis[i] + b2[lane];
}

// ================= launch =================

extern "C" void kernel_launch(void* const* d_in, const int* in_sizes, int n_in,
                              void* d_out, int out_size, void* d_ws, size_t ws_size,
                              hipStream_t stream) {
    const float* x  = (const float*)d_in[0];
    const int*   ei = (const int*)d_in[1];
    const float* W1 = (const float*)d_in[2];
    const float* b1 = (const float*)d_in[3];
    const float* W2 = (const float*)d_in[4];
    const float* b2 = (const float*)d_in[5];
    float* out = (float*)d_out;

    const int n = in_sizes[0] / IN_C;        // 100000
    const int E = in_sizes[1] / 2;           // 1600000
    const int* src = ei;
    const int* dst = ei + E;

    char* ws = (char*)d_ws;
    size_t off = 0;
    auto alloc = [&](size_t bytes) { char* p = ws + off; off += (bytes + 255) & ~(size_t)255; return p; };
    float* dis  = (float*)alloc((size_t)n * 4);
    int*   ptr  = (int*)  alloc((size_t)(n + 1) * 4);
    int*   col  = (int*)  alloc((size_t)E * 4);
    float* bufA = (float*)alloc((size_t)n * HID * 4);   // hs1, later hs2
    float* bufB = (float*)alloc((size_t)n * HID * 4);   // deg/fill/bsum then h1
    int* deg  = (int*)bufB;
    int* fill = (int*)bufB + n;
    int* bsum = (int*)bufB + 2 * n;

    const int nb = (n + 1023) / 1024;

    hipMemsetAsync(deg, 0, (size_t)n * 4, stream);
    deg_kernel<<<(E + 255) / 256, 256, 0, stream>>>(dst, deg, E);
    dis_kernel<<<(n + 255) / 256, 256, 0, stream>>>(deg, dis, n);
    scan_pass1<<<nb, 256, 0, stream>>>(deg, bsum, n);
    scan_pass2<<<1, 128, 0, stream>>>(bsum, nb);
    scan_pass3<<<nb, 256, 0, stream>>>(deg, bsum, ptr, fill, n, E);
    fill_kernel<<<(E + 255) / 256, 256, 0, stream>>>(src, dst, fill, col, E);

    gemm1_mfma<<<2048, 256, 0, stream>>>(x, W1, dis, bufA, n);
    agg1_kernel<<<(n + 3) / 4, 256, 0, stream>>>(ptr, col, bufA, dis, b1, bufB, n);
    gemm2_mfma<<<2048, 192, 0, stream>>>(bufB, W2, dis, bufA, n);
    agg2_kernel<<<(n + 3) / 4, 256, 0, stream>>>(ptr, col, bufA, dis, b2, out, n);
}

// Round 4
// 482.110 us; speedup vs baseline: 1.9671x; 1.1209x over previous
//
#include <hip/hip_runtime.h>

#define IN_C 128
#define HID  64
#define NCLS 40
#define CH   4096      // edges per scatter_part chunk

typedef float f32x4 __attribute__((ext_vector_type(4)));
typedef short s16x8 __attribute__((ext_vector_type(8)));

// truncation split: v = hi + lo with hi = top-16-bit truncation
static __device__ inline void split1(float v, unsigned short& hb, unsigned short& lb) {
    hb = (unsigned short)(__float_as_uint(v) >> 16);
    float vhi = __uint_as_float((unsigned)hb << 16);
    lb = (unsigned short)(__float_as_uint(v - vhi) >> 16);
}

static __device__ inline void split8(const f32x4 a0, const f32x4 a1, s16x8& hi, s16x8& lo) {
    float v[8] = {a0.x, a0.y, a0.z, a0.w, a1.x, a1.y, a1.z, a1.w};
#pragma unroll
    for (int j = 0; j < 8; ++j) {
        unsigned short hb, lb;
        split1(v[j], hb, lb);
        hi[j] = (short)hb;
        lo[j] = (short)lb;
    }
}

// ================= degree / normalization =================

__global__ void deg_kernel(const int* __restrict__ dst, int* __restrict__ deg, int E) {
    int e = blockIdx.x * blockDim.x + threadIdx.x;
    if (e < E) atomicAdd(&deg[dst[e]], 1);
}

__global__ void dis_kernel(const int* __restrict__ deg, float* __restrict__ dis, int n) {
    int i = blockIdx.x * blockDim.x + threadIdx.x;
    if (i < n) dis[i] = rsqrtf((float)(deg[i] + 1));   // +1 self-loop
}

// ================= exclusive scan of deg -> ptr (3-pass) =================

__global__ __launch_bounds__(256) void scan_pass1(
    const int* __restrict__ deg, int* __restrict__ bsum, int n)
{
    __shared__ int sdata[256];
    int base = blockIdx.x * 1024, t = threadIdx.x;
    int s = 0;
#pragma unroll
    for (int j = 0; j < 4; ++j) {
        int idx = base + t * 4 + j;
        if (idx < n) s += deg[idx];
    }
    sdata[t] = s; __syncthreads();
    for (int off = 128; off > 0; off >>= 1) {
        if (t < off) sdata[t] += sdata[t + off];
        __syncthreads();
    }
    if (t == 0) bsum[blockIdx.x] = sdata[0];
}

__global__ __launch_bounds__(128) void scan_pass2(int* __restrict__ bsum, int nb)
{
    __shared__ int sdata[128];
    int t = threadIdx.x;
    int v = (t < nb) ? bsum[t] : 0;
    sdata[t] = v; __syncthreads();
    for (int off = 1; off < 128; off <<= 1) {
        int add = (t >= off) ? sdata[t - off] : 0;
        __syncthreads();
        sdata[t] += add;
        __syncthreads();
    }
    if (t < nb) bsum[t] = sdata[t] - v;   // exclusive
}

__global__ __launch_bounds__(256) void scan_pass3(
    const int* __restrict__ deg, const int* __restrict__ bsum,
    int* __restrict__ ptr, int n, int E)
{
    __shared__ int sdata[256];
    int base = blockIdx.x * 1024, t = threadIdx.x;
    int v[4]; int ts = 0;
#pragma unroll
    for (int j = 0; j < 4; ++j) {
        int idx = base + t * 4 + j;
        v[j] = (idx < n) ? deg[idx] : 0;
        ts += v[j];
    }
    sdata[t] = ts; __syncthreads();
    for (int off = 1; off < 256; off <<= 1) {
        int add = (t >= off) ? sdata[t - off] : 0;
        __syncthreads();
        sdata[t] += add;
        __syncthreads();
    }
    int running = bsum[blockIdx.x] + sdata[t] - ts;
#pragma unroll
    for (int j = 0; j < 4; ++j) {
        int idx = base + t * 4 + j;
        if (idx < n) { ptr[idx] = running; running += v[j]; }
    }
    if (blockIdx.x == 0 && t == 0) ptr[n] = E;
}

// ================= bucket cursors: bfill[b] = ptr[b*128] =================

__global__ void bfill_init(const int* __restrict__ ptr, int* __restrict__ bfill, int n, int B) {
    int b = blockIdx.x * blockDim.x + threadIdx.x;
    if (b < B) bfill[b] = ptr[min(b << 7, n)];
}

// ================= coarse partition: part[] = edges grouped by dst>>7 ======
// packed word = (src << 7) | (dst & 127);  valid while n < 2^24

__global__ __launch_bounds__(256) void scatter_part(
    const int* __restrict__ src, const int* __restrict__ dst,
    int* __restrict__ bfill, int* __restrict__ part, int E, int B)
{
    __shared__ int cnt[1024], soff[1024], gpos[1024], sdata[256];
    __shared__ int stage[CH];
    const int t = threadIdx.x;
    const int base = blockIdx.x * CH;
    const int nE = min(CH, E - base);

    for (int i = t; i < 1024; i += 256) cnt[i] = 0;
    __syncthreads();
    // pass a: histogram by bucket
    for (int k = t; k < nE; k += 256)
        atomicAdd(&cnt[dst[base + k] >> 7], 1);
    __syncthreads();
    // block-exclusive scan of cnt[0..1023] (thread t owns 4t..4t+3)
    int v[4]; int ts = 0;
#pragma unroll
    for (int j = 0; j < 4; ++j) { v[j] = cnt[4 * t + j]; ts += v[j]; }
    sdata[t] = ts; __syncthreads();
    for (int off = 1; off < 256; off <<= 1) {
        int add = (t >= off) ? sdata[t - off] : 0;
        __syncthreads();
        sdata[t] += add;
        __syncthreads();
    }
    int run = sdata[t] - ts;
#pragma unroll
    for (int j = 0; j < 4; ++j) { soff[4 * t + j] = run; run += v[j]; }
    __syncthreads();
    // claim global runs (one atomic per non-empty (block,bucket))
    for (int b = t; b < B; b += 256) {
        int c = cnt[b];
        gpos[b] = c ? atomicAdd(&bfill[b], c) : 0;
    }
    __syncthreads();
    for (int i = t; i < 1024; i += 256) cnt[i] = 0;   // reuse as cursor
    __syncthreads();
    // pass b: bin into LDS stage
    for (int k = t; k < nE; k += 256) {
        int d = dst[base + k];
        int b = d >> 7;
        int p = atomicAdd(&cnt[b], 1);
        stage[soff[b] + p] = (src[base + k] << 7) | (d & 127);
    }
    __syncthreads();
    // copy per-bucket runs to global (contiguous stores per run)
    const int wave = t >> 6, lane = t & 63;
    for (int b = wave; b < B; b += 4) {
        int c = cnt[b];
        if (c == 0) continue;
        int sb = soff[b], gb = gpos[b];
        for (int j = lane; j < c; j += 64)
            part[gb + j] = stage[sb + j];
    }
}

// ================= fine sort within bucket -> CSR col ======================

__global__ __launch_bounds__(256) void fine_sort(
    const int* __restrict__ ptr, const int* __restrict__ part,
    int* __restrict__ col, int n)
{
    __shared__ int cur[128];
    __shared__ int stage[4608];        // 18 KB; avg bucket = 2046 edges
    const int t = threadIdx.x;
    const int base = blockIdx.x << 7;
    const int nn = min(128, n - base);
    const int rstart = ptr[base];
    const int rend = ptr[min(base + 128, n)];
    if (t < 128) cur[t] = (t < nn) ? (ptr[base + t] - rstart) : 0;
    __syncthreads();
    for (int e = rstart + t; e < rend; e += 256) {
        int pk = part[e];
        int p = atomicAdd(&cur[pk & 127], 1);
        int s = pk >> 7;
        if (p < 4608) stage[p] = s;
        else col[rstart + p] = s;      // overflow fallback (statistically never)
    }
    __syncthreads();
    int sz = rend - rstart; if (sz > 4608) sz = 4608;
    for (int j = t; j < sz; j += 256) col[rstart + j] = stage[j];
}

// ================= GEMM1 (MFMA): hs1 = (x @ W1) * dis[i] =================

__global__ __launch_bounds__(256) void gemm1_mfma(
    const float* __restrict__ x, const float* __restrict__ W1,
    const float* __restrict__ dis, float* __restrict__ hs1, int n)
{
    const int wave = threadIdx.x >> 6;
    const int lane = threadIdx.x & 63;
    const int m    = lane & 15;
    const int q    = lane >> 4;
    const int col  = wave * 16 + m;

    s16x8 bhi[4], blo[4];
#pragma unroll
    for (int t = 0; t < 4; ++t) {
#pragma unroll
        for (int j = 0; j < 8; ++j) {
            int k = t * 32 + q * 8 + j;
            unsigned short hb, lb;
            split1(W1[k * HID + col], hb, lb);
            bhi[t][j] = (short)hb;
            blo[t][j] = (short)lb;
        }
    }

    const int nslab = n >> 4;
    for (int s = blockIdx.x; s < nslab; s += gridDim.x) {
        const float* xrow = x + (size_t)(s * 16 + m) * IN_C;
        f32x4 acc = {0.f, 0.f, 0.f, 0.f};
#pragma unroll
        for (int t = 0; t < 4; ++t) {
            f32x4 a0 = *(const f32x4*)(xrow + t * 32 + q * 8);
            f32x4 a1 = *(const f32x4*)(xrow + t * 32 + q * 8 + 4);
            s16x8 ahi, alo;
            split8(a0, a1, ahi, alo);
            acc = __builtin_amdgcn_mfma_f32_16x16x32_bf16(ahi, bhi[t], acc, 0, 0, 0);
            acc = __builtin_amdgcn_mfma_f32_16x16x32_bf16(alo, bhi[t], acc, 0, 0, 0);
            acc = __builtin_amdgcn_mfma_f32_16x16x32_bf16(ahi, blo[t], acc, 0, 0, 0);
        }
#pragma unroll
        for (int r = 0; r < 4; ++r) {
            int row = s * 16 + q * 4 + r;
            hs1[(size_t)row * HID + col] = acc[r] * dis[row];
        }
    }
}

// ================= agg1 (fused self-loop + dis + bias + relu) =================

__global__ __launch_bounds__(256) void agg1_kernel(
    const int* __restrict__ ptr, const int* __restrict__ col,
    const float* __restrict__ hs1, const float* __restrict__ dis,
    const float* __restrict__ b1, float* __restrict__ h1, int n)
{
    int wave = threadIdx.x >> 6, lane = threadIdx.x & 63;
    int i = blockIdx.x * 4 + wave;
    if (i >= n) return;
    int start = ptr[i], end = ptr[i + 1];
    float acc = hs1[(size_t)i * HID + lane];      // self-loop term
    for (int base = start; base < end; base += 64) {
        int m = end - base; if (m > 64) m = 64;
        int myc = (lane < m) ? col[base + lane] : 0;
        for (int j = 0; j < m; ++j) {
            int s = __shfl(myc, j);
            acc += hs1[(size_t)s * HID + lane];
        }
    }
    float val = acc * dis[i] + b1[lane];
    h1[(size_t)i * HID + lane] = val > 0.f ? val : 0.f;
}

// ================= GEMM2 (MFMA): hs2 = (h1 @ W2) * dis[i] =================

__global__ __launch_bounds__(192) void gemm2_mfma(
    const float* __restrict__ h1, const float* __restrict__ W2,
    const float* __restrict__ dis, float* __restrict__ hs2, int n)
{
    const int wave = threadIdx.x >> 6;
    const int lane = threadIdx.x & 63;
    const int m    = lane & 15;
    const int q    = lane >> 4;
    const int col  = wave * 16 + m;

    s16x8 bhi[2], blo[2];
#pragma unroll
    for (int t = 0; t < 2; ++t) {
#pragma unroll
        for (int j = 0; j < 8; ++j) {
            int k = t * 32 + q * 8 + j;
            float w = (col < NCLS) ? W2[k * NCLS + col] : 0.f;
            unsigned short hb, lb;
            split1(w, hb, lb);
            bhi[t][j] = (short)hb;
            blo[t][j] = (short)lb;
        }
    }

    const int nslab = n >> 4;
    for (int s = blockIdx.x; s < nslab; s += gridDim.x) {
        const float* hrow = h1 + (size_t)(s * 16 + m) * HID;
        f32x4 acc = {0.f, 0.f, 0.f, 0.f};
#pragma unroll
        for (int t = 0; t < 2; ++t) {
            f32x4 a0 = *(const f32x4*)(hrow + t * 32 + q * 8);
            f32x4 a1 = *(const f32x4*)(hrow + t * 32 + q * 8 + 4);
            s16x8 ahi, alo;
            split8(a0, a1, ahi, alo);
            acc = __builtin_amdgcn_mfma_f32_16x16x32_bf16(ahi, bhi[t], acc, 0, 0, 0);
            acc = __builtin_amdgcn_mfma_f32_16x16x32_bf16(alo, bhi[t], acc, 0, 0, 0);
            acc = __builtin_amdgcn_mfma_f32_16x16x32_bf16(ahi, blo[t], acc, 0, 0, 0);
        }
        if (col < NCLS) {
#pragma unroll
            for (int r = 0; r < 4; ++r) {
                int row = s * 16 + q * 4 + r;
                hs2[(size_t)row * NCLS + col] = acc[r] * dis[row];
            }
        }
    }
}

// ================= agg2 (fused self-loop + dis + bias) -> out =================

__global__ __launch_bounds__(256) void agg2_kernel(
    const int* __restrict__ ptr, const int* __restrict__ col,
    const float* __restrict__ hs2, const float* __restrict__ dis,
    const float* __restrict__ b2, float* __restrict__ out, int n)
{
    int wave = threadIdx.x >> 6, lane = threadIdx.x & 63;
    int i = blockIdx.x * 4 + wave;
    if (i >= n) return;
    int start = ptr[i], end = ptr[i + 1];
    float acc = 0.f;
    if (lane < NCLS) acc = hs2[(size_t)i * NCLS + lane];   // self-loop
    for (int base = start; base < end; base += 64) {
        int m = end - base; if (m > 64) m = 64;
        int myc = (lane < m) ? col[base + lane] : 0;
        for (int j = 0; j < m; ++j) {
            int s = __shfl(myc, j);
            if (lane < NCLS) acc += hs2[(size_t)s * NCLS + lane];
        }
    }
    if (lane < NCLS) out[(size_t)i * NCLS + lane] = acc * dis[i] + b2[lane];
}

// ================= launch =================

extern "C" void kernel_launch(void* const* d_in, const int* in_sizes, int n_in,
                              void* d_out, int out_size, void* d_ws, size_t ws_size,
                              hipStream_t stream) {
    const float* x  = (const float*)d_in[0];
    const int*   ei = (const int*)d_in[1];
    const float* W1 = (const float*)d_in[2];
    const float* b1 = (const float*)d_in[3];
    const float* W2 = (const float*)d_in[4];
    const float* b2 = (const float*)d_in[5];
    float* out = (float*)d_out;

    const int n = in_sizes[0] / IN_C;        // 100000
    const int E = in_sizes[1] / 2;           // 1600000
    const int B = (n + 127) >> 7;            // 782 buckets of 128 nodes
    const int* src = ei;
    const int* dst = ei + E;

    char* ws = (char*)d_ws;
    size_t off = 0;
    auto alloc = [&](size_t bytes) { char* p = ws + off; off += (bytes + 255) & ~(size_t)255; return p; };
    float* dis  = (float*)alloc((size_t)n * 4);
    int*   ptr  = (int*)  alloc((size_t)(n + 1) * 4);
    int*   col  = (int*)  alloc((size_t)E * 4);
    float* bufA = (float*)alloc((size_t)n * HID * 4);   // hs1, later hs2
    float* bufB = (float*)alloc((size_t)n * HID * 4);   // transients, then h1
    // transients inside bufB (all dead before agg1 writes h1):
    int* deg   = (int*)bufB;                 // n ints
    int* bsum  = (int*)bufB + n;             // ~98 ints
    int* bfill = (int*)bufB + n + 512;       // B ints
    int* part  = (int*)bufB + n + 4096;      // E ints (coarse-partitioned edges)

    const int nb = (n + 1023) / 1024;        // 98

    hipMemsetAsync(deg, 0, (size_t)n * 4, stream);
    deg_kernel<<<(E + 255) / 256, 256, 0, stream>>>(dst, deg, E);
    dis_kernel<<<(n + 255) / 256, 256, 0, stream>>>(deg, dis, n);
    scan_pass1<<<nb, 256, 0, stream>>>(deg, bsum, n);
    scan_pass2<<<1, 128, 0, stream>>>(bsum, nb);
    scan_pass3<<<nb, 256, 0, stream>>>(deg, bsum, ptr, n, E);
    bfill_init<<<(B + 255) / 256, 256, 0, stream>>>(ptr, bfill, n, B);
    scatter_part<<<(E + CH - 1) / CH, 256, 0, stream>>>(src, dst, bfill, part, E, B);
    fine_sort<<<B, 256, 0, stream>>>(ptr, part, col, n);

    gemm1_mfma<<<2048, 256, 0, stream>>>(x, W1, dis, bufA, n);
    agg1_kernel<<<(n + 3) / 4, 256, 0, stream>>>(ptr, col, bufA, dis, b1, bufB, n);
    gemm2_mfma<<<2048, 192, 0, stream>>>(bufB, W2, dis, bufA, n);
    agg2_kernel<<<(n + 3) / 4, 256, 0, stream>>>(ptr, col, bufA, dis, b2, out, n);
}

// Round 5
// 400.367 us; speedup vs baseline: 2.3687x; 1.2042x over previous
//
#include <hip/hip_runtime.h>

#define IN_C 128
#define HID  64
#define NCLS 40
#define CH   4096      // edges per scatter_part chunk

typedef float f32x4 __attribute__((ext_vector_type(4)));
typedef short s16x8 __attribute__((ext_vector_type(8)));

// truncation split: v = hi + lo with hi = top-16-bit truncation
static __device__ inline void split1(float v, unsigned short& hb, unsigned short& lb) {
    hb = (unsigned short)(__float_as_uint(v) >> 16);
    float vhi = __uint_as_float((unsigned)hb << 16);
    lb = (unsigned short)(__float_as_uint(v - vhi) >> 16);
}

static __device__ inline void split8(const f32x4 a0, const f32x4 a1, s16x8& hi, s16x8& lo) {
    float v[8] = {a0.x, a0.y, a0.z, a0.w, a1.x, a1.y, a1.z, a1.w};
#pragma unroll
    for (int j = 0; j < 8; ++j) {
        unsigned short hb, lb;
        split1(v[j], hb, lb);
        hi[j] = (short)hb;
        lo[j] = (short)lb;
    }
}

// ================= degree / normalization =================

__global__ void deg_kernel(const int* __restrict__ dst, int* __restrict__ deg, int E) {
    int e = blockIdx.x * blockDim.x + threadIdx.x;
    if (e < E) atomicAdd(&deg[dst[e]], 1);
}

__global__ void dis_kernel(const int* __restrict__ deg, float* __restrict__ dis, int n) {
    int i = blockIdx.x * blockDim.x + threadIdx.x;
    if (i < n) dis[i] = rsqrtf((float)(deg[i] + 1));   // +1 self-loop
}

// ================= exclusive scan of deg -> ptr (3-pass) =================

__global__ __launch_bounds__(256) void scan_pass1(
    const int* __restrict__ deg, int* __restrict__ bsum, int n)
{
    __shared__ int sdata[256];
    int base = blockIdx.x * 1024, t = threadIdx.x;
    int s = 0;
#pragma unroll
    for (int j = 0; j < 4; ++j) {
        int idx = base + t * 4 + j;
        if (idx < n) s += deg[idx];
    }
    sdata[t] = s; __syncthreads();
    for (int off = 128; off > 0; off >>= 1) {
        if (t < off) sdata[t] += sdata[t + off];
        __syncthreads();
    }
    if (t == 0) bsum[blockIdx.x] = sdata[0];
}

__global__ __launch_bounds__(128) void scan_pass2(int* __restrict__ bsum, int nb)
{
    __shared__ int sdata[128];
    int t = threadIdx.x;
    int v = (t < nb) ? bsum[t] : 0;
    sdata[t] = v; __syncthreads();
    for (int off = 1; off < 128; off <<= 1) {
        int add = (t >= off) ? sdata[t - off] : 0;
        __syncthreads();
        sdata[t] += add;
        __syncthreads();
    }
    if (t < nb) bsum[t] = sdata[t] - v;   // exclusive
}

__global__ __launch_bounds__(256) void scan_pass3(
    const int* __restrict__ deg, const int* __restrict__ bsum,
    int* __restrict__ ptr, int n, int E)
{
    __shared__ int sdata[256];
    int base = blockIdx.x * 1024, t = threadIdx.x;
    int v[4]; int ts = 0;
#pragma unroll
    for (int j = 0; j < 4; ++j) {
        int idx = base + t * 4 + j;
        v[j] = (idx < n) ? deg[idx] : 0;
        ts += v[j];
    }
    sdata[t] = ts; __syncthreads();
    for (int off = 1; off < 256; off <<= 1) {
        int add = (t >= off) ? sdata[t - off] : 0;
        __syncthreads();
        sdata[t] += add;
        __syncthreads();
    }
    int running = bsum[blockIdx.x] + sdata[t] - ts;
#pragma unroll
    for (int j = 0; j < 4; ++j) {
        int idx = base + t * 4 + j;
        if (idx < n) { ptr[idx] = running; running += v[j]; }
    }
    if (blockIdx.x == 0 && t == 0) ptr[n] = E;
}

// ================= bucket cursors: bfill[b] = ptr[b*128] =================

__global__ void bfill_init(const int* __restrict__ ptr, int* __restrict__ bfill, int n, int B) {
    int b = blockIdx.x * blockDim.x + threadIdx.x;
    if (b < B) bfill[b] = ptr[min(b << 7, n)];
}

// ================= coarse partition: part[] = edges grouped by dst>>7 ======
// packed word = (src << 7) | (dst & 127);  valid while n < 2^24

__global__ __launch_bounds__(256) void scatter_part(
    const int* __restrict__ src, const int* __restrict__ dst,
    int* __restrict__ bfill, int* __restrict__ part, int E, int B)
{
    __shared__ int cnt[1024], soff[1024], gpos[1024], sdata[256];
    __shared__ int stage[CH];
    const int t = threadIdx.x;
    const int base = blockIdx.x * CH;
    const int nE = min(CH, E - base);

    for (int i = t; i < 1024; i += 256) cnt[i] = 0;
    __syncthreads();
    for (int k = t; k < nE; k += 256)
        atomicAdd(&cnt[dst[base + k] >> 7], 1);
    __syncthreads();
    int v[4]; int ts = 0;
#pragma unroll
    for (int j = 0; j < 4; ++j) { v[j] = cnt[4 * t + j]; ts += v[j]; }
    sdata[t] = ts; __syncthreads();
    for (int off = 1; off < 256; off <<= 1) {
        int add = (t >= off) ? sdata[t - off] : 0;
        __syncthreads();
        sdata[t] += add;
        __syncthreads();
    }
    int run = sdata[t] - ts;
#pragma unroll
    for (int j = 0; j < 4; ++j) { soff[4 * t + j] = run; run += v[j]; }
    __syncthreads();
    for (int b = t; b < B; b += 256) {
        int c = cnt[b];
        gpos[b] = c ? atomicAdd(&bfill[b], c) : 0;
    }
    __syncthreads();
    for (int i = t; i < 1024; i += 256) cnt[i] = 0;
    __syncthreads();
    for (int k = t; k < nE; k += 256) {
        int d = dst[base + k];
        int b = d >> 7;
        int p = atomicAdd(&cnt[b], 1);
        stage[soff[b] + p] = (src[base + k] << 7) | (d & 127);
    }
    __syncthreads();
    const int wave = t >> 6, lane = t & 63;
    for (int b = wave; b < B; b += 4) {
        int c = cnt[b];
        if (c == 0) continue;
        int sb = soff[b], gb = gpos[b];
        for (int j = lane; j < c; j += 64)
            part[gb + j] = stage[sb + j];
    }
}

// ================= fine sort within bucket -> CSR col ======================

__global__ __launch_bounds__(256) void fine_sort(
    const int* __restrict__ ptr, const int* __restrict__ part,
    int* __restrict__ col, int n)
{
    __shared__ int cur[128];
    __shared__ int stage[4608];
    const int t = threadIdx.x;
    const int base = blockIdx.x << 7;
    const int nn = min(128, n - base);
    const int rstart = ptr[base];
    const int rend = ptr[min(base + 128, n)];
    if (t < 128) cur[t] = (t < nn) ? (ptr[base + t] - rstart) : 0;
    __syncthreads();
    for (int e = rstart + t; e < rend; e += 256) {
        int pk = part[e];
        int p = atomicAdd(&cur[pk & 127], 1);
        int s = pk >> 7;
        if (p < 4608) stage[p] = s;
        else col[rstart + p] = s;
    }
    __syncthreads();
    int sz = rend - rstart; if (sz > 4608) sz = 4608;
    for (int j = t; j < sz; j += 256) col[rstart + j] = stage[j];
}

// ================= GEMM1 (MFMA): hs1 = (x @ W1) * dis[i] =================

__global__ __launch_bounds__(256) void gemm1_mfma(
    const float* __restrict__ x, const float* __restrict__ W1,
    const float* __restrict__ dis, float* __restrict__ hs1, int n)
{
    const int wave = threadIdx.x >> 6;
    const int lane = threadIdx.x & 63;
    const int m    = lane & 15;
    const int q    = lane >> 4;
    const int col  = wave * 16 + m;

    s16x8 bhi[4], blo[4];
#pragma unroll
    for (int t = 0; t < 4; ++t) {
#pragma unroll
        for (int j = 0; j < 8; ++j) {
            int k = t * 32 + q * 8 + j;
            unsigned short hb, lb;
            split1(W1[k * HID + col], hb, lb);
            bhi[t][j] = (short)hb;
            blo[t][j] = (short)lb;
        }
    }

    const int nslab = n >> 4;
    for (int s = blockIdx.x; s < nslab; s += gridDim.x) {
        const float* xrow = x + (size_t)(s * 16 + m) * IN_C;
        f32x4 acc = {0.f, 0.f, 0.f, 0.f};
#pragma unroll
        for (int t = 0; t < 4; ++t) {
            f32x4 a0 = *(const f32x4*)(xrow + t * 32 + q * 8);
            f32x4 a1 = *(const f32x4*)(xrow + t * 32 + q * 8 + 4);
            s16x8 ahi, alo;
            split8(a0, a1, ahi, alo);
            acc = __builtin_amdgcn_mfma_f32_16x16x32_bf16(ahi, bhi[t], acc, 0, 0, 0);
            acc = __builtin_amdgcn_mfma_f32_16x16x32_bf16(alo, bhi[t], acc, 0, 0, 0);
            acc = __builtin_amdgcn_mfma_f32_16x16x32_bf16(ahi, blo[t], acc, 0, 0, 0);
        }
#pragma unroll
        for (int r = 0; r < 4; ++r) {
            int row = s * 16 + q * 4 + r;
            hs1[(size_t)row * HID + col] = acc[r] * dis[row];
        }
    }
}

// ===== agg1: h1 = relu(dis*(gather-sum + self) + b1), 8-wide gather batches =====

__global__ __launch_bounds__(256) void agg1_kernel(
    const int* __restrict__ ptr, const int* __restrict__ col,
    const float* __restrict__ hs1, const float* __restrict__ dis,
    const float* __restrict__ b1, float* __restrict__ h1, int n)
{
    int wave = threadIdx.x >> 6, lane = threadIdx.x & 63;
    int i = blockIdx.x * 4 + wave;
    if (i >= n) return;
    int start = ptr[i], end = ptr[i + 1];
    float acc = hs1[(size_t)i * HID + lane];      // self-loop term
    for (int base = start; base < end; base += 64) {
        int m = end - base; if (m > 64) m = 64;
        int myc = (lane < m) ? col[base + lane] : 0;
        for (int j = 0; j < m; j += 8) {
            // always-full batch of 8 independent gathers; tail lanes re-read
            // edge 0's row with weight 0 so all 8 loads stay in flight
            float v[8];
#pragma unroll
            for (int u = 0; u < 8; ++u) {
                int jj = j + u;
                int s = __shfl(myc, jj < m ? jj : 0);
                float g = hs1[(size_t)s * HID + lane];
                v[u] = (jj < m) ? g : 0.f;
            }
            acc += ((v[0] + v[1]) + (v[2] + v[3])) + ((v[4] + v[5]) + (v[6] + v[7]));
        }
    }
    float val = acc * dis[i] + b1[lane];
    h1[(size_t)i * HID + lane] = val > 0.f ? val : 0.f;
}

// ================= GEMM2 (MFMA): hs2 = (h1 @ W2) * dis[i] =================

__global__ __launch_bounds__(192) void gemm2_mfma(
    const float* __restrict__ h1, const float* __restrict__ W2,
    const float* __restrict__ dis, float* __restrict__ hs2, int n)
{
    const int wave = threadIdx.x >> 6;
    const int lane = threadIdx.x & 63;
    const int m    = lane & 15;
    const int q    = lane >> 4;
    const int col  = wave * 16 + m;

    s16x8 bhi[2], blo[2];
#pragma unroll
    for (int t = 0; t < 2; ++t) {
#pragma unroll
        for (int j = 0; j < 8; ++j) {
            int k = t * 32 + q * 8 + j;
            float w = (col < NCLS) ? W2[k * NCLS + col] : 0.f;
            unsigned short hb, lb;
            split1(w, hb, lb);
            bhi[t][j] = (short)hb;
            blo[t][j] = (short)lb;
        }
    }

    const int nslab = n >> 4;
    for (int s = blockIdx.x; s < nslab; s += gridDim.x) {
        const float* hrow = h1 + (size_t)(s * 16 + m) * HID;
        f32x4 acc = {0.f, 0.f, 0.f, 0.f};
#pragma unroll
        for (int t = 0; t < 2; ++t) {
            f32x4 a0 = *(const f32x4*)(hrow + t * 32 + q * 8);
            f32x4 a1 = *(const f32x4*)(hrow + t * 32 + q * 8 + 4);
            s16x8 ahi, alo;
            split8(a0, a1, ahi, alo);
            acc = __builtin_amdgcn_mfma_f32_16x16x32_bf16(ahi, bhi[t], acc, 0, 0, 0);
            acc = __builtin_amdgcn_mfma_f32_16x16x32_bf16(alo, bhi[t], acc, 0, 0, 0);
            acc = __builtin_amdgcn_mfma_f32_16x16x32_bf16(ahi, blo[t], acc, 0, 0, 0);
        }
        if (col < NCLS) {
#pragma unroll
            for (int r = 0; r < 4; ++r) {
                int row = s * 16 + q * 4 + r;
                hs2[(size_t)row * NCLS + col] = acc[r] * dis[row];
            }
        }
    }
}

// ===== agg2: out = dis*(gather-sum + self) + b2, 8-wide gather batches =====
// lanes >= NCLS gather junk (in-bounds: buffer has >= n*HID floats) but never store.

__global__ __launch_bounds__(256) void agg2_kernel(
    const int* __restrict__ ptr, const int* __restrict__ col,
    const float* __restrict__ hs2, const float* __restrict__ dis,
    const float* __restrict__ b2, float* __restrict__ out, int n)
{
    int wave = threadIdx.x >> 6, lane = threadIdx.x & 63;
    int i = blockIdx.x * 4 + wave;
    if (i >= n) return;
    int start = ptr[i], end = ptr[i + 1];
    float acc = hs2[(size_t)i * NCLS + lane];
    for (int base = start; base < end; base += 64) {
        int m = end - base; if (m > 64) m = 64;
        int myc = (lane < m) ? col[base + lane] : 0;
        for (int j = 0; j < m; j += 8) {
            float v[8];
#pragma unroll
            for (int u = 0; u < 8; ++u) {
                int jj = j + u;
                int s = __shfl(myc, jj < m ? jj : 0);
                float g = hs2[(size_t)s * NCLS + lane];
                v[u] = (jj < m) ? g : 0.f;
            }
            acc += ((v[0] + v[1]) + (v[2] + v[3])) + ((v[4] + v[5]) + (v[6] + v[7]));
        }
    }
    if (lane < NCLS) out[(size_t)i * NCLS + lane] = acc * dis[i] + b2[lane];
}

// ================= launch =================

extern "C" void kernel_launch(void* const* d_in, const int* in_sizes, int n_in,
                              void* d_out, int out_size, void* d_ws, size_t ws_size,
                              hipStream_t stream) {
    const float* x  = (const float*)d_in[0];
    const int*   ei = (const int*)d_in[1];
    const float* W1 = (const float*)d_in[2];
    const float* b1 = (const float*)d_in[3];
    const float* W2 = (const float*)d_in[4];
    const float* b2 = (const float*)d_in[5];
    float* out = (float*)d_out;

    const int n = in_sizes[0] / IN_C;        // 100000
    const int E = in_sizes[1] / 2;           // 1600000
    const int B = (n + 127) >> 7;            // 782 buckets of 128 nodes
    const int* src = ei;
    const int* dst = ei + E;

    char* ws = (char*)d_ws;
    size_t off = 0;
    auto alloc = [&](size_t bytes) { char* p = ws + off; off += (bytes + 255) & ~(size_t)255; return p; };
    float* dis  = (float*)alloc((size_t)n * 4);
    int*   ptr  = (int*)  alloc((size_t)(n + 1) * 4);
    int*   col  = (int*)  alloc((size_t)E * 4);
    float* bufA = (float*)alloc((size_t)n * HID * 4);   // hs1, later hs2
    float* bufB = (float*)alloc((size_t)n * HID * 4);   // transients, then h1
    int* deg   = (int*)bufB;
    int* bsum  = (int*)bufB + n;
    int* bfill = (int*)bufB + n + 512;
    int* part  = (int*)bufB + n + 4096;

    const int nb = (n + 1023) / 1024;

    hipMemsetAsync(deg, 0, (size_t)n * 4, stream);
    deg_kernel<<<(E + 255) / 256, 256, 0, stream>>>(dst, deg, E);
    dis_kernel<<<(n + 255) / 256, 256, 0, stream>>>(deg, dis, n);
    scan_pass1<<<nb, 256, 0, stream>>>(deg, bsum, n);
    scan_pass2<<<1, 128, 0, stream>>>(bsum, nb);
    scan_pass3<<<nb, 256, 0, stream>>>(deg, bsum, ptr, n, E);
    bfill_init<<<(B + 255) / 256, 256, 0, stream>>>(ptr, bfill, n, B);
    scatter_part<<<(E + CH - 1) / CH, 256, 0, stream>>>(src, dst, bfill, part, E, B);
    fine_sort<<<B, 256, 0, stream>>>(ptr, part, col, n);

    gemm1_mfma<<<2048, 256, 0, stream>>>(x, W1, dis, bufA, n);
    agg1_kernel<<<(n + 3) / 4, 256, 0, stream>>>(ptr, col, bufA, dis, b1, bufB, n);
    gemm2_mfma<<<2048, 192, 0, stream>>>(bufB, W2, dis, bufA, n);
    agg2_kernel<<<(n + 3) / 4, 256, 0, stream>>>(ptr, col, bufA, dis, b2, out, n);
}

// Round 6
// 319.931 us; speedup vs baseline: 2.9642x; 1.2514x over previous
//
#include <hip/hip_runtime.h>

#define IN_C 128
#define HID  64
#define NCLS 40
#define CHP  2048     // edges per scatter_part chunk
#define CHH  4096     // edges per bhist chunk
#define NB   1024     // padded bucket-array size (B <= 1024)

typedef float f32x4 __attribute__((ext_vector_type(4)));
typedef short s16x8 __attribute__((ext_vector_type(8)));

// truncation split: v = hi + lo with hi = top-16-bit truncation
static __device__ inline void split1(float v, unsigned short& hb, unsigned short& lb) {
    hb = (unsigned short)(__float_as_uint(v) >> 16);
    float vhi = __uint_as_float((unsigned)hb << 16);
    lb = (unsigned short)(__float_as_uint(v - vhi) >> 16);
}

static __device__ inline void split8(const f32x4 a0, const f32x4 a1, s16x8& hi, s16x8& lo) {
    float v[8] = {a0.x, a0.y, a0.z, a0.w, a1.x, a1.y, a1.z, a1.w};
#pragma unroll
    for (int j = 0; j < 8; ++j) {
        unsigned short hb, lb;
        split1(v[j], hb, lb);
        hi[j] = (short)hb;
        lo[j] = (short)lb;
    }
}

// ================= bucket histogram: bcnt[b] = #edges with dst>>7 == b ======

__global__ __launch_bounds__(256) void bhist_kernel(
    const int* __restrict__ dst, int* __restrict__ bcnt, int E, int B)
{
    __shared__ int h[NB];
    const int t = threadIdx.x;
    for (int i = t; i < NB; i += 256) h[i] = 0;
    __syncthreads();
    const int base = blockIdx.x * CHH;
    const int nE = min(CHH, E - base);
    for (int k = t; k < nE; k += 256) atomicAdd(&h[dst[base + k] >> 7], 1);
    __syncthreads();
    for (int b = t; b < B; b += 256) { int c = h[b]; if (c) atomicAdd(&bcnt[b], c); }
}

// ================= bucket scan: bptr = exclusive scan(bcnt), bfill = copy ====

__global__ __launch_bounds__(256) void bscan_kernel(
    const int* __restrict__ bcnt, int* __restrict__ bptr, int* __restrict__ bfill,
    int B, int E)
{
    __shared__ int s[256];
    const int t = threadIdx.x;
    int v[4]; int ts = 0;
#pragma unroll
    for (int j = 0; j < 4; ++j) {
        int idx = 4 * t + j;
        v[j] = (idx < B) ? bcnt[idx] : 0;
        ts += v[j];
    }
    s[t] = ts; __syncthreads();
    for (int off = 1; off < 256; off <<= 1) {
        int add = (t >= off) ? s[t - off] : 0;
        __syncthreads();
        s[t] += add;
        __syncthreads();
    }
    int run = s[t] - ts;
#pragma unroll
    for (int j = 0; j < 4; ++j) {
        int idx = 4 * t + j;
        if (idx < B) { bptr[idx] = run; bfill[idx] = run; run += v[j]; }
    }
    if (t == 0) bptr[B] = E;
}

// ====== coarse partition: part[] = edges grouped by dst>>7 =================
// packed word = (src << 7) | (dst & 127)

__global__ __launch_bounds__(256) void scatter_part(
    const int* __restrict__ src, const int* __restrict__ dst,
    int* __restrict__ bfill, int* __restrict__ part, int E, int B)
{
    __shared__ int cnt[NB], soff[NB], gpos[NB], sdata[256];
    __shared__ int stage[CHP], destg[CHP];
    const int t = threadIdx.x;
    const int base = blockIdx.x * CHP;
    const int nE = min(CHP, E - base);

    for (int i = t; i < NB; i += 256) cnt[i] = 0;
    __syncthreads();
    // pass a: histogram by bucket
    for (int k = t; k < nE; k += 256)
        atomicAdd(&cnt[dst[base + k] >> 7], 1);
    __syncthreads();
    // block-exclusive scan of cnt[0..NB) (thread t owns 4t..4t+3)
    int v[4]; int ts = 0;
#pragma unroll
    for (int j = 0; j < 4; ++j) { v[j] = cnt[4 * t + j]; ts += v[j]; }
    sdata[t] = ts; __syncthreads();
    for (int off = 1; off < 256; off <<= 1) {
        int add = (t >= off) ? sdata[t - off] : 0;
        __syncthreads();
        sdata[t] += add;
        __syncthreads();
    }
    int run = sdata[t] - ts;
#pragma unroll
    for (int j = 0; j < 4; ++j) { soff[4 * t + j] = run; run += v[j]; }
    __syncthreads();
    // claim global runs (one atomic per non-empty (block,bucket))
    for (int b = t; b < B; b += 256) {
        int c = cnt[b];
        gpos[b] = c ? atomicAdd(&bfill[b], c) : 0;
    }
    __syncthreads();
    for (int i = t; i < NB; i += 256) cnt[i] = 0;   // reuse as cursor
    __syncthreads();
    // pass b: bin into LDS stage, record global destination
    for (int k = t; k < nE; k += 256) {
        int d = dst[base + k];
        int b = d >> 7;
        int p = atomicAdd(&cnt[b], 1);
        int o = soff[b] + p;
        stage[o] = (src[base + k] << 7) | (d & 127);
        destg[o] = gpos[b] + p;
    }
    __syncthreads();
    // full-width copy: consecutive k within a run -> consecutive destinations
    for (int k = t; k < nE; k += 256)
        part[destg[k]] = stage[k];
}

// ====== fine sort within bucket -> CSR col, per-node ptr & dis ==============

__global__ __launch_bounds__(256) void fine_sort(
    const int* __restrict__ bptr, const int* __restrict__ part,
    int* __restrict__ col, int* __restrict__ ptr, float* __restrict__ dis,
    int n, int E)
{
    __shared__ int cnt[128], sc[128], cur[128];
    __shared__ int stage[3072];        // avg bucket = 2046 edges, max ~2300
    const int t = threadIdx.x;
    const int base = blockIdx.x << 7;
    const int nn = min(128, n - base);
    const int rstart = bptr[blockIdx.x];
    const int rend   = bptr[blockIdx.x + 1];

    if (t < 128) cnt[t] = 0;
    __syncthreads();
    // per-node histogram (= in-degree)
    for (int e = rstart + t; e < rend; e += 256)
        atomicAdd(&cnt[part[e] & 127], 1);
    __syncthreads();
    // inclusive scan over 128 node counts
    int v = (t < 128) ? cnt[t] : 0;
    if (t < 128) sc[t] = v;
    __syncthreads();
    for (int off = 1; off < 128; off <<= 1) {
        int add = (t < 128 && t >= off) ? sc[t - off] : 0;
        __syncthreads();
        if (t < 128) sc[t] += add;
        __syncthreads();
    }
    if (t < 128) cur[t] = sc[t] - v;                  // exclusive
    if (t < nn) {
        ptr[base + t] = rstart + sc[t] - v;
        dis[base + t] = rsqrtf((float)(v + 1));       // +1 self-loop
    }
    if (blockIdx.x == 0 && t == 0) ptr[n] = E;
    __syncthreads();
    // scatter into LDS stage
    for (int e = rstart + t; e < rend; e += 256) {
        int pk = part[e];
        int p = atomicAdd(&cur[pk & 127], 1);
        int s = pk >> 7;
        if (p < 3072) stage[p] = s;
        else col[rstart + p] = s;                     // overflow fallback
    }
    __syncthreads();
    int sz = rend - rstart; if (sz > 3072) sz = 3072;
    for (int j = t; j < sz; j += 256) col[rstart + j] = stage[j];
}

// ================= GEMM1 (MFMA): hs1 = (x @ W1) * dis[i] =================

__global__ __launch_bounds__(256) void gemm1_mfma(
    const float* __restrict__ x, const float* __restrict__ W1,
    const float* __restrict__ dis, float* __restrict__ hs1, int n)
{
    const int wave = threadIdx.x >> 6;
    const int lane = threadIdx.x & 63;
    const int m    = lane & 15;
    const int q    = lane >> 4;
    const int col  = wave * 16 + m;

    s16x8 bhi[4], blo[4];
#pragma unroll
    for (int t = 0; t < 4; ++t) {
#pragma unroll
        for (int j = 0; j < 8; ++j) {
            int k = t * 32 + q * 8 + j;
            unsigned short hb, lb;
            split1(W1[k * HID + col], hb, lb);
            bhi[t][j] = (short)hb;
            blo[t][j] = (short)lb;
        }
    }

    const int nslab = n >> 4;
    for (int s = blockIdx.x; s < nslab; s += gridDim.x) {
        const float* xrow = x + (size_t)(s * 16 + m) * IN_C;
        f32x4 acc = {0.f, 0.f, 0.f, 0.f};
#pragma unroll
        for (int t = 0; t < 4; ++t) {
            f32x4 a0 = *(const f32x4*)(xrow + t * 32 + q * 8);
            f32x4 a1 = *(const f32x4*)(xrow + t * 32 + q * 8 + 4);
            s16x8 ahi, alo;
            split8(a0, a1, ahi, alo);
            acc = __builtin_amdgcn_mfma_f32_16x16x32_bf16(ahi, bhi[t], acc, 0, 0, 0);
            acc = __builtin_amdgcn_mfma_f32_16x16x32_bf16(alo, bhi[t], acc, 0, 0, 0);
            acc = __builtin_amdgcn_mfma_f32_16x16x32_bf16(ahi, blo[t], acc, 0, 0, 0);
        }
#pragma unroll
        for (int r = 0; r < 4; ++r) {
            int row = s * 16 + q * 4 + r;
            hs1[(size_t)row * HID + col] = acc[r] * dis[row];
        }
    }
}

// ===== agg1: h1 = relu(dis*(gather-sum + self) + b1), 8-wide gather batches =====

__global__ __launch_bounds__(256) void agg1_kernel(
    const int* __restrict__ ptr, const int* __restrict__ col,
    const float* __restrict__ hs1, const float* __restrict__ dis,
    const float* __restrict__ b1, float* __restrict__ h1, int n)
{
    int wave = threadIdx.x >> 6, lane = threadIdx.x & 63;
    int i = blockIdx.x * 4 + wave;
    if (i >= n) return;
    int start = ptr[i], end = ptr[i + 1];
    float acc = hs1[(size_t)i * HID + lane];      // self-loop term
    for (int base = start; base < end; base += 64) {
        int m = end - base; if (m > 64) m = 64;
        int myc = (lane < m) ? col[base + lane] : 0;
        for (int j = 0; j < m; j += 8) {
            float v[8];
#pragma unroll
            for (int u = 0; u < 8; ++u) {
                int jj = j + u;
                int s = __shfl(myc, jj < m ? jj : 0);
                float g = hs1[(size_t)s * HID + lane];
                v[u] = (jj < m) ? g : 0.f;
            }
            acc += ((v[0] + v[1]) + (v[2] + v[3])) + ((v[4] + v[5]) + (v[6] + v[7]));
        }
    }
    float val = acc * dis[i] + b1[lane];
    h1[(size_t)i * HID + lane] = val > 0.f ? val : 0.f;
}

// ================= GEMM2 (MFMA): hs2 = (h1 @ W2) * dis[i] =================

__global__ __launch_bounds__(192) void gemm2_mfma(
    const float* __restrict__ h1, const float* __restrict__ W2,
    const float* __restrict__ dis, float* __restrict__ hs2, int n)
{
    const int wave = threadIdx.x >> 6;
    const int lane = threadIdx.x & 63;
    const int m    = lane & 15;
    const int q    = lane >> 4;
    const int col  = wave * 16 + m;

    s16x8 bhi[2], blo[2];
#pragma unroll
    for (int t = 0; t < 2; ++t) {
#pragma unroll
        for (int j = 0; j < 8; ++j) {
            int k = t * 32 + q * 8 + j;
            float w = (col < NCLS) ? W2[k * NCLS + col] : 0.f;
            unsigned short hb, lb;
            split1(w, hb, lb);
            bhi[t][j] = (short)hb;
            blo[t][j] = (short)lb;
        }
    }

    const int nslab = n >> 4;
    for (int s = blockIdx.x; s < nslab; s += gridDim.x) {
        const float* hrow = h1 + (size_t)(s * 16 + m) * HID;
        f32x4 acc = {0.f, 0.f, 0.f, 0.f};
#pragma unroll
        for (int t = 0; t < 2; ++t) {
            f32x4 a0 = *(const f32x4*)(hrow + t * 32 + q * 8);
            f32x4 a1 = *(const f32x4*)(hrow + t * 32 + q * 8 + 4);
            s16x8 ahi, alo;
            split8(a0, a1, ahi, alo);
            acc = __builtin_amdgcn_mfma_f32_16x16x32_bf16(ahi, bhi[t], acc, 0, 0, 0);
            acc = __builtin_amdgcn_mfma_f32_16x16x32_bf16(alo, bhi[t], acc, 0, 0, 0);
            acc = __builtin_amdgcn_mfma_f32_16x16x32_bf16(ahi, blo[t], acc, 0, 0, 0);
        }
        if (col < NCLS) {
#pragma unroll
            for (int r = 0; r < 4; ++r) {
                int row = s * 16 + q * 4 + r;
                hs2[(size_t)row * NCLS + col] = acc[r] * dis[row];
            }
        }
    }
}

// ===== agg2: out = dis*(gather-sum + self) + b2, 8-wide gather batches =====

__global__ __launch_bounds__(256) void agg2_kernel(
    const int* __restrict__ ptr, const int* __restrict__ col,
    const float* __restrict__ hs2, const float* __restrict__ dis,
    const float* __restrict__ b2, float* __restrict__ out, int n)
{
    int wave = threadIdx.x >> 6, lane = threadIdx.x & 63;
    int i = blockIdx.x * 4 + wave;
    if (i >= n) return;
    int start = ptr[i], end = ptr[i + 1];
    float acc = hs2[(size_t)i * NCLS + lane];
    for (int base = start; base < end; base += 64) {
        int m = end - base; if (m > 64) m = 64;
        int myc = (lane < m) ? col[base + lane] : 0;
        for (int j = 0; j < m; j += 8) {
            float v[8];
#pragma unroll
            for (int u = 0; u < 8; ++u) {
                int jj = j + u;
                int s = __shfl(myc, jj < m ? jj : 0);
                float g = hs2[(size_t)s * NCLS + lane];
                v[u] = (jj < m) ? g : 0.f;
            }
            acc += ((v[0] + v[1]) + (v[2] + v[3])) + ((v[4] + v[5]) + (v[6] + v[7]));
        }
    }
    if (lane < NCLS) out[(size_t)i * NCLS + lane] = acc * dis[i] + b2[lane];
}

// ================= launch =================

extern "C" void kernel_launch(void* const* d_in, const int* in_sizes, int n_in,
                              void* d_out, int out_size, void* d_ws, size_t ws_size,
                              hipStream_t stream) {
    const float* x  = (const float*)d_in[0];
    const int*   ei = (const int*)d_in[1];
    const float* W1 = (const float*)d_in[2];
    const float* b1 = (const float*)d_in[3];
    const float* W2 = (const float*)d_in[4];
    const float* b2 = (const float*)d_in[5];
    float* out = (float*)d_out;

    const int n = in_sizes[0] / IN_C;        // 100000
    const int E = in_sizes[1] / 2;           // 1600000
    const int B = (n + 127) >> 7;            // 782 buckets of 128 nodes
    const int* src = ei;
    const int* dst = ei + E;

    char* ws = (char*)d_ws;
    size_t off = 0;
    auto alloc = [&](size_t bytes) { char* p = ws + off; off += (bytes + 255) & ~(size_t)255; return p; };
    float* dis  = (float*)alloc((size_t)n * 4);
    int*   ptr  = (int*)  alloc((size_t)(n + 1) * 4);
    int*   col  = (int*)  alloc((size_t)E * 4);
    int*   bcnt = (int*)  alloc((size_t)NB * 4);
    int*   bptr = (int*)  alloc((size_t)(NB + 1) * 4);
    int*   bfill= (int*)  alloc((size_t)NB * 4);
    float* bufA = (float*)alloc((size_t)n * HID * 4);   // hs1, later hs2
    float* bufB = (float*)alloc((size_t)n * HID * 4);   // part (transient), then h1
    int* part = (int*)bufB;                   // E ints, dead before agg1 writes h1

    hipMemsetAsync(bcnt, 0, (size_t)B * 4, stream);
    bhist_kernel<<<(E + CHH - 1) / CHH, 256, 0, stream>>>(dst, bcnt, E, B);
    bscan_kernel<<<1, 256, 0, stream>>>(bcnt, bptr, bfill, B, E);
    scatter_part<<<(E + CHP - 1) / CHP, 256, 0, stream>>>(src, dst, bfill, part, E, B);
    fine_sort<<<B, 256, 0, stream>>>(bptr, part, col, ptr, dis, n, E);

    gemm1_mfma<<<2048, 256, 0, stream>>>(x, W1, dis, bufA, n);
    agg1_kernel<<<(n + 3) / 4, 256, 0, stream>>>(ptr, col, bufA, dis, b1, bufB, n);
    gemm2_mfma<<<2048, 192, 0, stream>>>(bufB, W2, dis, bufA, n);
    agg2_kernel<<<(n + 3) / 4, 256, 0, stream>>>(ptr, col, bufA, dis, b2, out, n);
}